// Round 1
// baseline (216.378 us; speedup 1.0000x reference)
//
#include <hip/hip_runtime.h>
#include <stdint.h>

#define BB 4096
#define TT 200
#define DD 128
#define HH 128

typedef __attribute__((ext_vector_type(8))) short bf16x8;
typedef __attribute__((ext_vector_type(4))) float f32x4;

__device__ __forceinline__ short f2bf(float f) {
    uint32_t u = __builtin_bit_cast(uint32_t, f);
    u += 0x7fffu + ((u >> 16) & 1u);   // RNE
    return (short)(u >> 16);
}
__device__ __forceinline__ uint32_t pk2(float a, float b) {
    uint32_t r;
    asm("v_cvt_pk_bf16_f32 %0, %1, %2" : "=v"(r) : "v"(a), "v"(b));
    return r;
}
__device__ __forceinline__ float sigm(float x) {
    return __builtin_amdgcn_rcpf(1.0f + __expf(-x));
}
__device__ __forceinline__ float tanhf_(float x) {
    return 2.0f * __builtin_amdgcn_rcpf(1.0f + __expf(-2.0f * x)) - 1.0f;
}
// LDS-only barrier: drain lgkm (our ds ops), NOT vmcnt -> global prefetch
// stays in flight across the barrier (T4 counted-vmcnt lesson).
__device__ __forceinline__ void bar_lds() {
    asm volatile("s_waitcnt lgkmcnt(0)" ::: "memory");
    __builtin_amdgcn_sched_barrier(0);
    __builtin_amdgcn_s_barrier();
    __builtin_amdgcn_sched_barrier(0);
}

// LDS layout: [16 rows][16 granules] of bf16x8 (16B granules, 256B row stride),
// granule XOR-swizzled by (row&7). Fragment read (row c, granule kt*4+grp) is a
// single conflict-free ds_read_b128: bank-quad = ((kt*4+grp)^(c&7))&7 spreads the
// 64 lanes exactly 8 per quad. uint2 writes land 8 lanes per quad (balanced).

// One AUGRU step. Phase A: stage x(T+1), reissue prefetch, recurrent z/r MFMA,
// sigmoid, stage r*h. Phase B: h_tilde MFMA + next-step feed-forward MFMA,
// tanh, h update + bf16 mirror.
#define STEP(T, XR) { \
    const int sn_ = ((T) + 1) & 1; \
    *(uint2*)((short*)&xbuf[sn_][xrow][xg_swz] + xhalf) = \
        make_uint2(pk2(XR.x, XR.y), pk2(XR.z, XR.w)); \
    { const int t3_ = ((T) + 3 < TT) ? (T) + 3 : TT - 1; \
      XR = *(const float4*)(xsrc + (size_t)t3_ * DD); } \
    bf16x8 hf_[4]; \
    _Pragma("unroll") \
    for (int kt = 0; kt < 4; ++kt) hf_[kt] = hrow[fg[kt]]; \
    f32x4 az_ = pz, ar_ = pr; \
    _Pragma("unroll") \
    for (int kt = 0; kt < 4; ++kt) { \
        az_ = __builtin_amdgcn_mfma_f32_16x16x32_bf16(Wf[0][1][kt], hf_[kt], az_, 0, 0, 0); \
        ar_ = __builtin_amdgcn_mfma_f32_16x16x32_bf16(Wf[1][1][kt], hf_[kt], ar_, 0, 0, 0); \
    } \
    f32x4 zv_, rhv_; \
    _Pragma("unroll") \
    for (int r = 0; r < 4; ++r) { zv_[r] = sigm(az_[r]); rhv_[r] = sigm(ar_[r]) * hreg[r]; } \
    *(uint2*)((short*)&rhbuf[c][g_out_swz] + ohalf) = \
        make_uint2(pk2(rhv_[0], rhv_[1]), pk2(rhv_[2], rhv_[3])); \
    bar_lds(); \
    const float a_c_ = attbuf[c][(T)]; \
    bf16x8 rf_[4], xf2_[4]; \
    { const bf16x8* xp2_ = &xbuf[sn_][c][0]; \
      _Pragma("unroll") \
      for (int kt = 0; kt < 4; ++kt) { \
          rf_[kt]  = rhrow[fg[kt]]; \
          xf2_[kt] = xp2_[fg[kt]]; \
      } } \
    f32x4 ah_ = ph; \
    _Pragma("unroll") \
    for (int kt = 0; kt < 4; ++kt) \
        ah_ = __builtin_amdgcn_mfma_f32_16x16x32_bf16(Wf[2][1][kt], rf_[kt], ah_, 0, 0, 0); \
    pz = bzv; pr = brv; ph = bhv; \
    _Pragma("unroll") \
    for (int kt = 0; kt < 4; ++kt) { \
        pz = __builtin_amdgcn_mfma_f32_16x16x32_bf16(Wf[0][0][kt], xf2_[kt], pz, 0, 0, 0); \
        pr = __builtin_amdgcn_mfma_f32_16x16x32_bf16(Wf[1][0][kt], xf2_[kt], pr, 0, 0, 0); \
        ph = __builtin_amdgcn_mfma_f32_16x16x32_bf16(Wf[2][0][kt], xf2_[kt], ph, 0, 0, 0); \
    } \
    _Pragma("unroll") \
    for (int r = 0; r < 4; ++r) { \
        float ht_ = tanhf_(ah_[r]); \
        float zp_ = a_c_ * zv_[r]; \
        hreg[r] = __builtin_fmaf(zp_, ht_ - hreg[r], hreg[r]); \
    } \
    *(uint2*)((short*)&hbuf[c][g_out_swz] + ohalf) = \
        make_uint2(pk2(hreg[0], hreg[1]), pk2(hreg[2], hreg[3])); \
    bar_lds(); \
}

__global__ __launch_bounds__(512, 2) void augru_kernel(
    const float* __restrict__ inp,   // [B,T,D]
    const float* __restrict__ att,   // [B,T]
    const float* __restrict__ h0,    // [B,H]
    const float* __restrict__ Wz, const float* __restrict__ bz,
    const float* __restrict__ Wr, const float* __restrict__ br,
    const float* __restrict__ Wh, const float* __restrict__ bh,
    float* __restrict__ out)         // [B,H]
{
    __shared__ bf16x8 xbuf[2][16][16];   // x(t) bf16, swizzled granules
    __shared__ bf16x8 hbuf[16][16];      // h(t) bf16 mirror, swizzled
    __shared__ bf16x8 rhbuf[16][16];     // r*h staging, swizzled
    __shared__ float attbuf[16][201];    // whole att tile, padded (conflict-free)

    const int tid  = threadIdx.x;
    const int wave = tid >> 6;
    const int lane = tid & 63;
    const int c    = lane & 15;          // batch row
    const int grp  = lane >> 4;          // k-group
    const int wbase = wave * 16;
    const int ocol  = wbase + grp * 4;   // this thread's 4 output columns
    const int rowbase = blockIdx.x * 16;

    // swizzle constants (loop-invariant)
    const int swz = c & 7;
    const int fg[4] = { (0 + grp) ^ swz, (4 + grp) ^ swz,
                        (8 + grp) ^ swz, (12 + grp) ^ swz };
    const int g_out_swz = (wave * 2 + (grp >> 1)) ^ swz;  // granule of ocol, swizzled
    const int ohalf = (grp & 1) * 4;                      // short offset within granule
    const bf16x8* hrow  = &hbuf[c][0];
    const bf16x8* rhrow = &rhbuf[c][0];

    // ---------------- weights -> register fragments ----------------
    bf16x8 Wf[3][2][4];
    {
        const float* Wp[3] = {Wz, Wr, Wh};
        #pragma unroll
        for (int g3 = 0; g3 < 3; ++g3) {
            #pragma unroll
            for (int p = 0; p < 2; ++p) {
                #pragma unroll
                for (int kt = 0; kt < 4; ++kt) {
                    bf16x8 v;
                    #pragma unroll
                    for (int j = 0; j < 8; ++j) {
                        int k = p * 128 + kt * 32 + grp * 8 + j;
                        v[j] = f2bf(Wp[g3][(size_t)k * HH + wbase + c]);
                    }
                    Wf[g3][p][kt] = v;
                }
            }
        }
    }
    f32x4 bzv, brv, bhv;
    #pragma unroll
    for (int r = 0; r < 4; ++r) {
        bzv[r] = bz[ocol + r];
        brv[r] = br[ocol + r];
        bhv[r] = bh[ocol + r];
    }

    // ---------------- att tile -> LDS (one-time, coalesced) ----------------
    for (int idx = tid; idx < 16 * TT; idx += 512)
        attbuf[idx / TT][idx % TT] = att[(size_t)rowbase * TT + idx];

    // ---------------- h state ----------------
    f32x4 hreg;
    {
        float4 hv = *(const float4*)&h0[(size_t)(rowbase + c) * HH + ocol];
        hreg[0] = hv.x; hreg[1] = hv.y; hreg[2] = hv.z; hreg[3] = hv.w;
        *(uint2*)((short*)&hbuf[c][g_out_swz] + ohalf) =
            make_uint2(pk2(hv.x, hv.y), pk2(hv.z, hv.w));
    }

    // ---------------- x(0) stage; xrA=x(1), xrB=x(2) prefetch ----------------
    const int xrow = tid >> 5;
    const int xc4  = (tid & 31) * 4;
    const int xg_swz = ((tid & 31) >> 1) ^ (xrow & 7);   // granule of xc4, swizzled
    const int xhalf  = (tid & 1) * 4;
    const float* xsrc = inp + ((size_t)(rowbase + xrow) * TT) * DD + xc4;
    {
        float4 x0 = *(const float4*)(xsrc);
        *(uint2*)((short*)&xbuf[0][xrow][xg_swz] + xhalf) =
            make_uint2(pk2(x0.x, x0.y), pk2(x0.z, x0.w));
    }
    float4 xrA = *(const float4*)(xsrc + DD);
    float4 xrB = *(const float4*)(xsrc + 2 * DD);
    __syncthreads();

    // pre(0): feed-forward x-parts
    f32x4 pz = bzv, pr = brv, ph = bhv;
    {
        const bf16x8* x0p = &xbuf[0][c][0];
        bf16x8 xf[4];
        #pragma unroll
        for (int kt = 0; kt < 4; ++kt) xf[kt] = x0p[fg[kt]];
        #pragma unroll
        for (int kt = 0; kt < 4; ++kt) {
            pz = __builtin_amdgcn_mfma_f32_16x16x32_bf16(Wf[0][0][kt], xf[kt], pz, 0, 0, 0);
            pr = __builtin_amdgcn_mfma_f32_16x16x32_bf16(Wf[1][0][kt], xf[kt], pr, 0, 0, 0);
            ph = __builtin_amdgcn_mfma_f32_16x16x32_bf16(Wf[2][0][kt], xf[kt], ph, 0, 0, 0);
        }
    }

    // ---------------- scan (unrolled x2: xrA even steps, xrB odd) ----------------
    for (int t = 0; t < TT; t += 2) {
        STEP(t, xrA);
        STEP(t + 1, xrB);
    }

    // ---------------- store h_final ----------------
    float4 o; o.x = hreg[0]; o.y = hreg[1]; o.z = hreg[2]; o.w = hreg[3];
    *(float4*)&out[(size_t)(rowbase + c) * HH + ocol] = o;
}

extern "C" void kernel_launch(void* const* d_in, const int* in_sizes, int n_in,
                              void* d_out, int out_size, void* d_ws, size_t ws_size,
                              hipStream_t stream) {
    const float* inp = (const float*)d_in[0];
    const float* att = (const float*)d_in[1];
    const float* h0  = (const float*)d_in[2];
    const float* Wz  = (const float*)d_in[3];
    const float* bz  = (const float*)d_in[4];
    const float* Wr  = (const float*)d_in[5];
    const float* br  = (const float*)d_in[6];
    const float* Wh  = (const float*)d_in[7];
    const float* bh  = (const float*)d_in[8];
    float* out = (float*)d_out;

    dim3 grid(BB / 16), block(512);
    augru_kernel<<<grid, block, 0, stream>>>(inp, att, h0, Wz, bz, Wr, br, Wh, bh, out);
}